// Round 14
// baseline (311.565 us; speedup 1.0000x reference)
//
#include <hip/hip_runtime.h>
#include <math.h>

#define BLK 256

typedef unsigned short ushort;
typedef unsigned int uint;
typedef __attribute__((ext_vector_type(8))) short short8;
typedef __attribute__((ext_vector_type(4))) float f32x4;

constexpr int C_Hc = 128;
constexpr int C_INc = 64;
constexpr int Hh = 128;
constexpr int Ww = 128;
constexpr int HWc = Hh * Ww;   // 16384
constexpr int Bb = 2;
constexpr float EPSV = 1e-5f;

__device__ __forceinline__ float bf2f(ushort u) {
    union { uint u32; float f; } v; v.u32 = (uint)u << 16; return v.f;
}
__device__ __forceinline__ ushort f2bf(float x) {
    union { float f; uint u; } v; v.f = x;
    uint r = (v.u + 0x7FFFu + ((v.u >> 16) & 1u)) >> 16;
    return (ushort)r;
}
__device__ __forceinline__ uint pack2(float a, float b) {
    return (uint)f2bf(a) | ((uint)f2bf(b) << 16);
}
__device__ __forceinline__ void gload16(const ushort* g, ushort* l) {
    __builtin_amdgcn_global_load_lds(
        (const __attribute__((address_space(1))) void*)g,
        (__attribute__((address_space(3))) void*)l, 16, 0, 0);
}

// ---------------------------------------------------------------------------
// Weight prep (chunk-major bf16) — exact R5/R9 version.
// ---------------------------------------------------------------------------
__global__ __launch_bounds__(BLK) void k_prep(
    const float* __restrict__ w1, const float* __restrict__ w2,
    const float* __restrict__ wsp,
    ushort* __restrict__ wA, ushort* __restrict__ w2b,
    ushort* __restrict__ wspb)
{
    int idx = blockIdx.x * BLK + threadIdx.x;
    if (idx < 147456) {                       // wA: 9 * 16384
        int tap = idx >> 14, r = idx & 16383;
        int chunk = r >> 10, co = (r >> 3) & 127, e = r & 7;
        int ci = chunk * 8 + e;
        wA[idx] = f2bf(w1[(co * 128 + ci) * 9 + tap]);
    } else if (idx < 557056) {                // w2b: 25 * 16384
        int o = idx - 147456;
        int k = o >> 14, r = o & 16383;
        int chunk = r >> 10, co = (r >> 3) & 127, e = r & 7;
        int ci = chunk * 8 + e;
        w2b[o] = f2bf(w2[(co * 25 + k) * 128 + ci]);
    } else if (idx < 573440) {                // wspb: 16384
        int o = idx - 557056;
        int chunk = o >> 10, co = (o >> 3) & 127, e = o & 7;
        wspb[o] = f2bf(wsp[co * 128 + chunk * 8 + e]);
    }
}

// ---------------------------------------------------------------------------
// conv1x1(w_in) + LayerNorm — exact R11/R12 version (LDS-transposed stores).
// ---------------------------------------------------------------------------
__global__ __launch_bounds__(BLK) void k_in_ln(
    const float* __restrict__ xr, const float* __restrict__ xe,
    const float* __restrict__ w_in, const float* __restrict__ lng,
    const float* __restrict__ lnb,
    ushort* __restrict__ fTr, ushort* __restrict__ fTe,
    float* __restrict__ featrT)
{
    int bid  = blockIdx.x;          // 2 * Bb * 256
    int simg = bid >> 9;
    int rem  = bid & 511;
    int b    = rem >> 8;
    int base = (rem & 255) * 64;
    const float* x = simg ? xe : xr;
    ushort* fT = simg ? fTe : fTr;
    int tid  = threadIdx.x;
    int lane = tid & 63;
    int cg   = tid >> 6;

    __shared__ float xs[C_INc][64];
    __shared__ float r1[4][64], r2[4][64];
    __shared__ ushort lb[64][136];     // bf16 [px][ch] transpose, padded row
    __shared__ float  lf[64][132];     // fp32 [px][ch] transpose, padded row

    #pragma unroll
    for (int r = 0; r < 16; ++r) {
        int i = cg * 16 + r;
        xs[i][lane] = x[(b * C_INc + i) * HWc + base + lane];
    }
    __syncthreads();

    float acc[32];
    #pragma unroll
    for (int cc = 0; cc < 32; ++cc) acc[cc] = 0.f;

    for (int i4 = 0; i4 < 16; ++i4) {
        float x0 = xs[i4 * 4 + 0][lane];
        float x1 = xs[i4 * 4 + 1][lane];
        float x2 = xs[i4 * 4 + 2][lane];
        float x3 = xs[i4 * 4 + 3][lane];
        #pragma unroll
        for (int cc = 0; cc < 32; ++cc) {
            float4 wv = *reinterpret_cast<const float4*>(
                &w_in[(cg * 32 + cc) * C_INc + i4 * 4]);
            acc[cc] += wv.x * x0 + wv.y * x1 + wv.z * x2 + wv.w * x3;
        }
    }

    float s1 = 0.f, s2 = 0.f;
    #pragma unroll
    for (int cc = 0; cc < 32; ++cc) { s1 += acc[cc]; s2 += acc[cc] * acc[cc]; }
    r1[cg][lane] = s1; r2[cg][lane] = s2;
    __syncthreads();
    float m   = (r1[0][lane] + r1[1][lane] + r1[2][lane] + r1[3][lane]) * (1.f / C_Hc);
    float ex2 = (r2[0][lane] + r2[1][lane] + r2[2][lane] + r2[3][lane]) * (1.f / C_Hc);
    float rs  = rsqrtf(ex2 - m * m + EPSV);

    #pragma unroll
    for (int cc = 0; cc < 32; cc += 4) {
        int c0 = cg * 32 + cc;
        float4 g4 = *reinterpret_cast<const float4*>(&lng[c0]);
        float4 b4 = *reinterpret_cast<const float4*>(&lnb[c0]);
        float4 y;
        y.x = (acc[cc + 0] - m) * rs * g4.x + b4.x;
        y.y = (acc[cc + 1] - m) * rs * g4.y + b4.y;
        y.z = (acc[cc + 2] - m) * rs * g4.z + b4.z;
        y.w = (acc[cc + 3] - m) * rs * g4.w + b4.w;
        *reinterpret_cast<uint*>(&lb[lane][c0])     = pack2(y.x, y.y);
        *reinterpret_cast<uint*>(&lb[lane][c0 + 2]) = pack2(y.z, y.w);
        if (!simg)
            *reinterpret_cast<float4*>(&lf[lane][c0]) = y;
    }
    __syncthreads();

    long long tb = ((long long)((b << 14) + base)) << 7;   // ushort index
    #pragma unroll
    for (int t = 0; t < 4; ++t) {
        int j  = tid + (t << 8);          // 0..1023
        int px = j >> 4;                  // 0..63
        int w0 = (j & 15) << 3;           // ushort offset 0..120
        uint4 v = *reinterpret_cast<const uint4*>(&lb[px][w0]);
        *reinterpret_cast<uint4*>(&fT[tb + ((long long)px << 7) + w0]) = v;
    }
    if (!simg) {
        #pragma unroll
        for (int t = 0; t < 8; ++t) {
            int j  = tid + (t << 8);      // 0..2047
            int px = j >> 5;              // 0..63
            int w0 = (j & 31) << 2;       // float offset 0..124
            float4 v = *reinterpret_cast<const float4*>(&lf[px][w0]);
            *reinterpret_cast<float4*>(&featrT[tb + ((long long)px << 7) + w0]) = v;
        }
    }
}

// ---------------------------------------------------------------------------
// conv3x3 + ReLU — exact R13 half-row version (proven bit-identical).
// ---------------------------------------------------------------------------
__global__ __launch_bounds__(BLK, 3) void k_conv3(
    const ushort* __restrict__ fTr, const ushort* __restrict__ fTe,
    const ushort* __restrict__ wA,
    ushort* __restrict__ hTr, ushort* __restrict__ hTe)
{
    int bid = blockIdx.x;           // 2s * 2b * 128 rows * 2 halves = 1024
    int ph = bid & 1, h0 = (bid >> 1) & 127, b = (bid >> 8) & 1, s = bid >> 9;
    int w0 = ph << 6;
    const ushort* fT = s ? fTe : fTr;
    ushort* hT = s ? hTe : hTr;
    int tid = threadIdx.x, lane = tid & 63, wv = tid >> 6;
    int lpx = lane & 15, lk = lane >> 4;
    int co0 = wv * 32;

    __shared__ ushort ft[16 * 198 * 8];     // [chunk][row*66+col][8]  (50,688 B)

    const long long ibase = (long long)(b << 14);

    for (int i = tid; i < 16 * 198; i += BLK) {
        int chunk = i / 198;
        int rem = i - chunk * 198;
        int row = rem / 66, col = rem - row * 66;
        int gh = h0 + row - 1, gw = w0 + col - 1;
        uint4 v = make_uint4(0, 0, 0, 0);
        if ((unsigned)gh < 128u && (unsigned)gw < 128u)
            v = *reinterpret_cast<const uint4*>(
                &fT[((ibase + (gh << 7) + gw) << 7) + (chunk << 3)]);
        *reinterpret_cast<uint4*>(&ft[i << 3]) = v;
    }
    __syncthreads();

    f32x4 acc[2][4];
    #pragma unroll
    for (int f = 0; f < 2; ++f)
        #pragma unroll
        for (int p = 0; p < 4; ++p) acc[f][p] = f32x4{0.f, 0.f, 0.f, 0.f};

    for (int tap = 0; tap < 9; ++tap) {
        int ki = tap / 3, kj = tap - ki * 3;
        const ushort* wtp = &wA[tap << 14];
        short8 a[2][4];
        #pragma unroll
        for (int f = 0; f < 2; ++f) {
            int co = co0 + f * 16 + lpx;
            #pragma unroll
            for (int q = 0; q < 4; ++q)
                a[f][q] = *reinterpret_cast<const short8*>(
                    &wtp[(((q * 4 + lk) << 7) + co) << 3]);
        }
        #pragma unroll
        for (int p = 0; p < 4; ++p) {
            int col = p * 16 + lpx + kj;           // 0..65
            short8 bq[4];
            #pragma unroll
            for (int q = 0; q < 4; ++q)
                bq[q] = *reinterpret_cast<const short8*>(
                    &ft[((q * 4 + lk) * 198 + ki * 66 + col) << 3]);
            #pragma unroll
            for (int f = 0; f < 2; ++f)
                #pragma unroll
                for (int q = 0; q < 4; ++q)
                    acc[f][p] = __builtin_amdgcn_mfma_f32_16x16x32_bf16(
                        a[f][q], bq[q], acc[f][p], 0, 0, 0);
        }
    }

    long long obase = (ibase + ((long long)h0 << 7)) << 7;
    #pragma unroll
    for (int f = 0; f < 2; ++f)
        #pragma unroll
        for (int p = 0; p < 4; ++p) {
            int c  = co0 + f * 16 + (lk << 2);
            int px = w0 + p * 16 + lpx;
            float v0 = fmaxf(acc[f][p][0], 0.f), v1 = fmaxf(acc[f][p][1], 0.f);
            float v2 = fmaxf(acc[f][p][2], 0.f), v3 = fmaxf(acc[f][p][3], 0.f);
            ushort* dst = &hT[obase + ((long long)px << 7) + c];
            *reinterpret_cast<uint*>(&dst[0]) = pack2(v0, v1);
            *reinterpret_cast<uint*>(&dst[2]) = pack2(v2, v3);
        }
}

// ---------------------------------------------------------------------------
// Fused dynamic-filter v14.  R12/R13 math EXACTLY (per-element FP chain
// unchanged -> bit-identical).  Restructured for occupancy: block = 1 row
// (512 thr, 8 waves, wave tile 64co x 32px); wk SINGLE-buffered 32 KB +
// fr single row 32 KB = 64 KB LDS -> 2 blocks/CU (16 waves/CU, 4/SIMD).
// Per tap: compute -> barrier -> DMA next weights (+row at group edge) ->
// barrier; the co-resident block hides the DMA latency.
// ---------------------------------------------------------------------------
__global__ __launch_bounds__(512, 4) void k_dfapply(
    const ushort* __restrict__ hTr, const ushort* __restrict__ hTe,
    const ushort* __restrict__ fTr, const ushort* __restrict__ fTe,
    const ushort* __restrict__ w2b,
    ushort* __restrict__ enhr, ushort* __restrict__ enhe)
{
    int bid = blockIdx.x;           // 2s * 2b * 128 rows = 512
    int s = bid >> 8, b = (bid >> 7) & 1, h0 = bid & 127;
    const ushort* hT = s ? hTe : hTr;
    const ushort* fT = s ? fTe : fTr;
    ushort* enh = s ? enhe : enhr;
    int tid = threadIdx.x, lane = tid & 63, wv = tid >> 6;
    int lpx = lane & 15, lk = lane >> 4;
    int co0 = (wv & 1) * 64, px0 = (wv >> 1) * 32;

    __shared__ ushort wk[16 * 128 * 8];      // 32 KB weights (single buffer)
    __shared__ ushort fr[128 * 16 * 8];      // 32 KB feat row (swizzled)

    const long long ibase = (long long)(b << 14);
    const long long rowbase = (ibase + ((long long)h0 << 7)) << 7;

    // persistent B fragments (h tile, 32px x 128ci) from global (L2)
    short8 bq[2][4];
    #pragma unroll
    for (int p = 0; p < 2; ++p) {
        int px = px0 + p * 16 + lpx;
        #pragma unroll
        for (int q = 0; q < 4; ++q)
            bq[p][q] = *reinterpret_cast<const short8*>(
                &hT[rowbase + ((long long)px << 7) + ((q * 4 + lk) << 3)]);
    }

    // stage feat row h0+dh into fr (pre-swizzled source: su = u ^ (px&15))
    auto stage_row = [&](int dh) {
        int gh = h0 + dh;
        if ((unsigned)gh < 128u) {
            const ushort* rowsrc = fT + ((ibase + ((long long)gh << 7)) << 7);
            #pragma unroll
            for (int t = 0; t < 4; ++t) {
                int j = tid + (t << 9);          // 0..2047
                int px = j >> 4, u = j & 15;
                int su = u ^ (px & 15);
                gload16(&rowsrc[(px << 7) + (su << 3)], &fr[j << 3]);
            }
        }
    };

    // prologue: weights for k=0 + row for dh=-2
    #pragma unroll
    for (int t = 0; t < 4; ++t) {
        int j = tid + (t << 9);
        gload16(&w2b[j << 3], &wk[j << 3]);
    }
    stage_row(-2);
    __syncthreads();

    f32x4 osum[4][2];
    #pragma unroll
    for (int f = 0; f < 4; ++f)
        #pragma unroll
        for (int p = 0; p < 2; ++p) osum[f][p] = f32x4{0.f, 0.f, 0.f, 0.f};

    for (int k = 0; k < 25; ++k) {
        int k5 = k / 5;
        int dh = k5 - 2, dw = k - k5 * 5 - 2;
        int gh = h0 + dh;
        bool rowok = (unsigned)gh < 128u;

        uint2 featv[2][4];
        #pragma unroll
        for (int p = 0; p < 2; ++p) {
            int gw = px0 + p * 16 + lpx + dw;
            bool ok = rowok && ((unsigned)gw < 128u);
            #pragma unroll
            for (int f = 0; f < 4; ++f) {
                int c4 = co0 + f * 16 + (lk << 2);
                uint2 v = make_uint2(0, 0);
                if (ok) v = *reinterpret_cast<const uint2*>(
                    &fr[(((gw << 4) + ((c4 >> 3) ^ (gw & 15))) << 3)
                        + (c4 & 7)]);
                featv[p][f] = v;
            }
        }

        #pragma unroll
        for (int f = 0; f < 4; ++f) {
            int co = co0 + f * 16 + lpx;
            short8 a[4];
            #pragma unroll
            for (int q = 0; q < 4; ++q)
                a[q] = *reinterpret_cast<const short8*>(
                    &wk[(((q * 4 + lk) << 7) + co) << 3]);
            __builtin_amdgcn_s_setprio(1);
            #pragma unroll
            for (int p = 0; p < 2; ++p) {
                f32x4 fac = f32x4{0.f, 0.f, 0.f, 0.f};
                #pragma unroll
                for (int q = 0; q < 4; ++q)
                    fac = __builtin_amdgcn_mfma_f32_16x16x32_bf16(
                        a[q], bq[p][q], fac, 0, 0, 0);
                uint2 fv = featv[p][f];
                osum[f][p][0] += fac[0] * bf2f((ushort)(fv.x & 0xffff));
                osum[f][p][1] += fac[1] * bf2f((ushort)(fv.x >> 16));
                osum[f][p][2] += fac[2] * bf2f((ushort)(fv.y & 0xffff));
                osum[f][p][3] += fac[3] * bf2f((ushort)(fv.y >> 16));
            }
            __builtin_amdgcn_s_setprio(0);
        }
        __syncthreads();             // all reads of wk/fr done
        if (k < 24) {
            const ushort* srcb = &w2b[(k + 1) << 14];
            #pragma unroll
            for (int t = 0; t < 4; ++t) {
                int j = tid + (t << 9);
                gload16(&srcb[j << 3], &wk[j << 3]);
            }
            if (k - k5 * 5 == 4)     // group boundary: next dh's row
                stage_row(k5 - 1);   // dh_next = (k+1)/5 - 2 = k5 - 1
            __syncthreads();         // DMA landed (vmcnt drained)
        }
    }

    // park osum in fr at [px][chunk ^ (px&15)][8] (bf16, same values)
    #pragma unroll
    for (int f = 0; f < 4; ++f)
        #pragma unroll
        for (int p = 0; p < 2; ++p) {
            int c  = co0 + f * 16 + (lk << 2);
            int px = px0 + p * 16 + lpx;
            int slot = (c >> 3) ^ (px & 15);
            uint2 o;
            o.x = pack2(osum[f][p][0], osum[f][p][1]);
            o.y = pack2(osum[f][p][2], osum[f][p][3]);
            *reinterpret_cast<uint2*>(
                &fr[(((px << 4) + slot) << 3) + (c & 7)]) = o;
        }
    __syncthreads();

    // coalesced enh stores: per 16-lane group one px's 256B window
    #pragma unroll
    for (int t = 0; t < 4; ++t) {
        int j  = tid + (t << 9);          // 0..2047
        int px = j >> 4, u = j & 15;
        int chunk = u ^ (px & 15);
        uint4 v = *reinterpret_cast<const uint4*>(&fr[j << 3]);
        *reinterpret_cast<uint4*>(
            &enh[rowbase + ((long long)px << 7) + (chunk << 3)]) = v;
    }
}

// ---------------------------------------------------------------------------
// Tail — exact R10..R13 version (proven).
// ---------------------------------------------------------------------------
__global__ __launch_bounds__(BLK, 2) void k_final(
    const ushort* __restrict__ enhr, const ushort* __restrict__ enhe,
    const float* __restrict__ featrT,
    const ushort* __restrict__ wspb, const float* __restrict__ w_out,
    const float* __restrict__ lng, const float* __restrict__ lnb,
    float* __restrict__ out)
{
    int bid = blockIdx.x;            // Bb * 256
    int b = bid >> 8;
    int px0g = (bid & 255) * 64;
    int tid = threadIdx.x, lane = tid & 63, wv = tid >> 6;
    int lpx = lane & 15, lk = lane >> 4;

    __shared__ float woA[4096];
    __shared__ float woB[4096];
    __shared__ float xs[128][64];
    __shared__ float p1[4][64], p2[4][64];
    ushort* es = (ushort*)woA;

    const long long ebase = ((long long)((b << 14) + px0g)) << 7;

    #pragma unroll
    for (int t = 0; t < 4; ++t) {
        int j = tid + (t << 8);
        int chunk = j >> 6, px = j & 63;
        *reinterpret_cast<uint4*>(&es[j << 3]) =
            *reinterpret_cast<const uint4*>(
                &enhe[ebase + ((long long)px << 7) + (chunk << 3)]);
    }
    __syncthreads();

    int co0 = wv * 32;
    f32x4 sp[2][4];
    #pragma unroll
    for (int f = 0; f < 2; ++f)
        #pragma unroll
        for (int p = 0; p < 4; ++p) sp[f][p] = f32x4{0.f, 0.f, 0.f, 0.f};
    #pragma unroll
    for (int q = 0; q < 4; ++q) {
        short8 a[2], bb[4];
        #pragma unroll
        for (int f = 0; f < 2; ++f)
            a[f] = *reinterpret_cast<const short8*>(
                &wspb[((((q * 4 + lk) << 7) + co0 + f * 16 + lpx)) << 3]);
        #pragma unroll
        for (int p = 0; p < 4; ++p)
            bb[p] = *reinterpret_cast<const short8*>(
                &es[((((q * 4 + lk) << 6) + p * 16 + lpx)) << 3]);
        #pragma unroll
        for (int f = 0; f < 2; ++f)
            #pragma unroll
            for (int p = 0; p < 4; ++p)
                sp[f][p] = __builtin_amdgcn_mfma_f32_16x16x32_bf16(
                    a[f], bb[p], sp[f][p], 0, 0, 0);
    }

    float fu[2][4][4];
    float s1[4] = {0.f, 0.f, 0.f, 0.f}, s2[4] = {0.f, 0.f, 0.f, 0.f};
    #pragma unroll
    for (int f = 0; f < 2; ++f) {
        int c4 = co0 + f * 16 + (lk << 2);
        #pragma unroll
        for (int p = 0; p < 4; ++p) {
            int px = p * 16 + lpx;
            long long poff = ebase + ((long long)px << 7) + c4;
            uint2 re2 = *reinterpret_cast<const uint2*>(&enhr[poff]);
            float4 rf4 = *reinterpret_cast<const float4*>(&featrT[poff]);
            float re[4] = { bf2f((ushort)(re2.x & 0xffff)), bf2f((ushort)(re2.x >> 16)),
                            bf2f((ushort)(re2.y & 0xffff)), bf2f((ushort)(re2.y >> 16)) };
            float rf[4] = { rf4.x, rf4.y, rf4.z, rf4.w };
            #pragma unroll
            for (int rr = 0; rr < 4; ++rr) {
                float sg = 1.f / (1.f + __expf(-sp[f][p][rr]));
                float v = re[rr] * (1.f + sg) + rf[rr];
                fu[f][p][rr] = v;
                s1[p] += v; s2[p] += v * v;
            }
        }
    }
    #pragma unroll
    for (int p = 0; p < 4; ++p) {
        s1[p] += __shfl_xor(s1[p], 16); s1[p] += __shfl_xor(s1[p], 32);
        s2[p] += __shfl_xor(s2[p], 16); s2[p] += __shfl_xor(s2[p], 32);
    }
    if (lk == 0) {
        #pragma unroll
        for (int p = 0; p < 4; ++p) {
            p1[wv][p * 16 + lpx] = s1[p];
            p2[wv][p * 16 + lpx] = s2[p];
        }
    }
    __syncthreads();

    #pragma unroll
    for (int i = 0; i < 8; ++i) {
        int fidx = tid + (i << 8);
        float4 v = *reinterpret_cast<const float4*>(&w_out[fidx << 2]);
        if (fidx < 1024) reinterpret_cast<float4*>(woA)[fidx] = v;
        else             reinterpret_cast<float4*>(woB)[fidx - 1024] = v;
    }

    float mm[4], rs[4];
    #pragma unroll
    for (int p = 0; p < 4; ++p) {
        int px = p * 16 + lpx;
        float m   = (p1[0][px] + p1[1][px] + p1[2][px] + p1[3][px]) * (1.f / 128.f);
        float ex2 = (p2[0][px] + p2[1][px] + p2[2][px] + p2[3][px]) * (1.f / 128.f);
        mm[p] = m;
        rs[p] = rsqrtf(ex2 - m * m + EPSV);
    }

    #pragma unroll
    for (int f = 0; f < 2; ++f) {
        int c4 = co0 + f * 16 + (lk << 2);
        float4 g = *reinterpret_cast<const float4*>(&lng[c4]);
        float4 bta = *reinterpret_cast<const float4*>(&lnb[c4]);
        #pragma unroll
        for (int p = 0; p < 4; ++p) {
            int px = p * 16 + lpx;
            xs[c4 + 0][px] = (fu[f][p][0] - mm[p]) * rs[p] * g.x + bta.x;
            xs[c4 + 1][px] = (fu[f][p][1] - mm[p]) * rs[p] * g.y + bta.y;
            xs[c4 + 2][px] = (fu[f][p][2] - mm[p]) * rs[p] * g.z + bta.z;
            xs[c4 + 3][px] = (fu[f][p][3] - mm[p]) * rs[p] * g.w + bta.w;
        }
    }
    __syncthreads();

    int co0o = wv * 16;
    const float* wop = (wv & 2) ? woB : woA;
    int wbase = (wv & 1) << 11;
    float oacc[16];
    #pragma unroll
    for (int oo = 0; oo < 16; ++oo) oacc[oo] = 0.f;
    for (int j4 = 0; j4 < 32; ++j4) {
        float x0 = xs[j4 * 4 + 0][lane];
        float x1 = xs[j4 * 4 + 1][lane];
        float x2 = xs[j4 * 4 + 2][lane];
        float x3 = xs[j4 * 4 + 3][lane];
        #pragma unroll
        for (int oo = 0; oo < 16; ++oo) {
            float4 wv4 = *reinterpret_cast<const float4*>(
                &wop[wbase + oo * C_Hc + j4 * 4]);
            oacc[oo] += wv4.x * x0 + wv4.y * x1 + wv4.z * x2 + wv4.w * x3;
        }
    }
    #pragma unroll
    for (int oo = 0; oo < 16; ++oo)
        out[((long long)(b * C_INc + co0o + oo) << 14) + px0g + lane] = oacc[oo];
}

// ---------------------------------------------------------------------------
extern "C" void kernel_launch(void* const* d_in, const int* in_sizes, int n_in,
                              void* d_out, int out_size, void* d_ws, size_t ws_size,
                              hipStream_t stream)
{
    const float* rgb  = (const float*)d_in[0];
    const float* evt  = (const float*)d_in[1];
    const float* w_in = (const float*)d_in[2];
    const float* lng  = (const float*)d_in[3];
    const float* lnb  = (const float*)d_in[4];
    const float* w1   = (const float*)d_in[5];
    const float* w2   = (const float*)d_in[6];
    const float* wsp  = (const float*)d_in[7];
    const float* wout = (const float*)d_in[8];
    float* out = (float*)d_out;

    float* ws = (float*)d_ws;
    ushort* fTr    = (ushort*)(ws);
    ushort* fTe    = (ushort*)(ws + 2097152);
    ushort* hTr    = (ushort*)(ws + 4194304);
    ushort* hTe    = (ushort*)(ws + 6291456);
    ushort* enhr   = (ushort*)(ws + 8388608);
    ushort* enhe   = (ushort*)(ws + 10485760);
    float*  featrT = (float*)(ws + 12582912);   // 4,194,304 f (fp32 NHWC, rgb)
    ushort* wA     = (ushort*)(ws + 16777216);  // 147456 bf16
    ushort* w2b    = (ushort*)(ws + 16850944);  // 409600 bf16
    ushort* wspb   = (ushort*)(ws + 17055744);  // 16384 bf16

    k_prep<<<2240, BLK, 0, stream>>>(w1, w2, wsp, wA, w2b, wspb);
    k_in_ln<<<2 * Bb * 256, BLK, 0, stream>>>(rgb, evt, w_in, lng, lnb,
                                              fTr, fTe, featrT);
    k_conv3<<<1024, BLK, 0, stream>>>(fTr, fTe, wA, hTr, hTe);
    k_dfapply<<<512, 512, 0, stream>>>(hTr, hTe, fTr, fTe, w2b, enhr, enhe);
    k_final<<<Bb * 256, BLK, 0, stream>>>(enhr, enhe, featrT, wspb, wout,
                                          lng, lnb, out);
}

// Round 15
// 213.275 us; speedup vs baseline: 1.4609x; 1.4609x over previous
//
#include <hip/hip_runtime.h>
#include <math.h>

#define BLK 256

typedef unsigned short ushort;
typedef unsigned int uint;
typedef __attribute__((ext_vector_type(8))) short short8;
typedef __attribute__((ext_vector_type(4))) float f32x4;

constexpr int C_Hc = 128;
constexpr int C_INc = 64;
constexpr int Hh = 128;
constexpr int Ww = 128;
constexpr int HWc = Hh * Ww;   // 16384
constexpr int Bb = 2;
constexpr float EPSV = 1e-5f;

__device__ __forceinline__ float bf2f(ushort u) {
    union { uint u32; float f; } v; v.u32 = (uint)u << 16; return v.f;
}
__device__ __forceinline__ ushort f2bf(float x) {
    union { float f; uint u; } v; v.f = x;
    uint r = (v.u + 0x7FFFu + ((v.u >> 16) & 1u)) >> 16;
    return (ushort)r;
}
__device__ __forceinline__ uint pack2(float a, float b) {
    return (uint)f2bf(a) | ((uint)f2bf(b) << 16);
}
__device__ __forceinline__ void gload16(const ushort* g, ushort* l) {
    __builtin_amdgcn_global_load_lds(
        (const __attribute__((address_space(1))) void*)g,
        (__attribute__((address_space(3))) void*)l, 16, 0, 0);
}

// ---------------------------------------------------------------------------
// Weight prep (chunk-major bf16) — exact R5/R9 version.
// ---------------------------------------------------------------------------
__global__ __launch_bounds__(BLK) void k_prep(
    const float* __restrict__ w1, const float* __restrict__ w2,
    const float* __restrict__ wsp,
    ushort* __restrict__ wA, ushort* __restrict__ w2b,
    ushort* __restrict__ wspb)
{
    int idx = blockIdx.x * BLK + threadIdx.x;
    if (idx < 147456) {                       // wA: 9 * 16384
        int tap = idx >> 14, r = idx & 16383;
        int chunk = r >> 10, co = (r >> 3) & 127, e = r & 7;
        int ci = chunk * 8 + e;
        wA[idx] = f2bf(w1[(co * 128 + ci) * 9 + tap]);
    } else if (idx < 557056) {                // w2b: 25 * 16384
        int o = idx - 147456;
        int k = o >> 14, r = o & 16383;
        int chunk = r >> 10, co = (r >> 3) & 127, e = r & 7;
        int ci = chunk * 8 + e;
        w2b[o] = f2bf(w2[(co * 25 + k) * 128 + ci]);
    } else if (idx < 573440) {                // wspb: 16384
        int o = idx - 557056;
        int chunk = o >> 10, co = (o >> 3) & 127, e = o & 7;
        wspb[o] = f2bf(wsp[co * 128 + chunk * 8 + e]);
    }
}

// ---------------------------------------------------------------------------
// conv1x1(w_in) + LayerNorm — exact R11/R12 version (LDS-transposed stores).
// ---------------------------------------------------------------------------
__global__ __launch_bounds__(BLK) void k_in_ln(
    const float* __restrict__ xr, const float* __restrict__ xe,
    const float* __restrict__ w_in, const float* __restrict__ lng,
    const float* __restrict__ lnb,
    ushort* __restrict__ fTr, ushort* __restrict__ fTe,
    float* __restrict__ featrT)
{
    int bid  = blockIdx.x;          // 2 * Bb * 256
    int simg = bid >> 9;
    int rem  = bid & 511;
    int b    = rem >> 8;
    int base = (rem & 255) * 64;
    const float* x = simg ? xe : xr;
    ushort* fT = simg ? fTe : fTr;
    int tid  = threadIdx.x;
    int lane = tid & 63;
    int cg   = tid >> 6;

    __shared__ float xs[C_INc][64];
    __shared__ float r1[4][64], r2[4][64];
    __shared__ ushort lb[64][136];     // bf16 [px][ch] transpose, padded row
    __shared__ float  lf[64][132];     // fp32 [px][ch] transpose, padded row

    #pragma unroll
    for (int r = 0; r < 16; ++r) {
        int i = cg * 16 + r;
        xs[i][lane] = x[(b * C_INc + i) * HWc + base + lane];
    }
    __syncthreads();

    float acc[32];
    #pragma unroll
    for (int cc = 0; cc < 32; ++cc) acc[cc] = 0.f;

    for (int i4 = 0; i4 < 16; ++i4) {
        float x0 = xs[i4 * 4 + 0][lane];
        float x1 = xs[i4 * 4 + 1][lane];
        float x2 = xs[i4 * 4 + 2][lane];
        float x3 = xs[i4 * 4 + 3][lane];
        #pragma unroll
        for (int cc = 0; cc < 32; ++cc) {
            float4 wv = *reinterpret_cast<const float4*>(
                &w_in[(cg * 32 + cc) * C_INc + i4 * 4]);
            acc[cc] += wv.x * x0 + wv.y * x1 + wv.z * x2 + wv.w * x3;
        }
    }

    float s1 = 0.f, s2 = 0.f;
    #pragma unroll
    for (int cc = 0; cc < 32; ++cc) { s1 += acc[cc]; s2 += acc[cc] * acc[cc]; }
    r1[cg][lane] = s1; r2[cg][lane] = s2;
    __syncthreads();
    float m   = (r1[0][lane] + r1[1][lane] + r1[2][lane] + r1[3][lane]) * (1.f / C_Hc);
    float ex2 = (r2[0][lane] + r2[1][lane] + r2[2][lane] + r2[3][lane]) * (1.f / C_Hc);
    float rs  = rsqrtf(ex2 - m * m + EPSV);

    #pragma unroll
    for (int cc = 0; cc < 32; cc += 4) {
        int c0 = cg * 32 + cc;
        float4 g4 = *reinterpret_cast<const float4*>(&lng[c0]);
        float4 b4 = *reinterpret_cast<const float4*>(&lnb[c0]);
        float4 y;
        y.x = (acc[cc + 0] - m) * rs * g4.x + b4.x;
        y.y = (acc[cc + 1] - m) * rs * g4.y + b4.y;
        y.z = (acc[cc + 2] - m) * rs * g4.z + b4.z;
        y.w = (acc[cc + 3] - m) * rs * g4.w + b4.w;
        *reinterpret_cast<uint*>(&lb[lane][c0])     = pack2(y.x, y.y);
        *reinterpret_cast<uint*>(&lb[lane][c0 + 2]) = pack2(y.z, y.w);
        if (!simg)
            *reinterpret_cast<float4*>(&lf[lane][c0]) = y;
    }
    __syncthreads();

    long long tb = ((long long)((b << 14) + base)) << 7;   // ushort index
    #pragma unroll
    for (int t = 0; t < 4; ++t) {
        int j  = tid + (t << 8);          // 0..1023
        int px = j >> 4;                  // 0..63
        int w0 = (j & 15) << 3;           // ushort offset 0..120
        uint4 v = *reinterpret_cast<const uint4*>(&lb[px][w0]);
        *reinterpret_cast<uint4*>(&fT[tb + ((long long)px << 7) + w0]) = v;
    }
    if (!simg) {
        #pragma unroll
        for (int t = 0; t < 8; ++t) {
            int j  = tid + (t << 8);      // 0..2047
            int px = j >> 5;              // 0..63
            int w0 = (j & 31) << 2;       // float offset 0..124
            float4 v = *reinterpret_cast<const float4*>(&lf[px][w0]);
            *reinterpret_cast<float4*>(&featrT[tb + ((long long)px << 7) + w0]) = v;
        }
    }
}

// ---------------------------------------------------------------------------
// conv3x3 + ReLU — exact R13 half-row version (proven bit-identical).
// ---------------------------------------------------------------------------
__global__ __launch_bounds__(BLK, 3) void k_conv3(
    const ushort* __restrict__ fTr, const ushort* __restrict__ fTe,
    const ushort* __restrict__ wA,
    ushort* __restrict__ hTr, ushort* __restrict__ hTe)
{
    int bid = blockIdx.x;           // 2s * 2b * 128 rows * 2 halves = 1024
    int ph = bid & 1, h0 = (bid >> 1) & 127, b = (bid >> 8) & 1, s = bid >> 9;
    int w0 = ph << 6;
    const ushort* fT = s ? fTe : fTr;
    ushort* hT = s ? hTe : hTr;
    int tid = threadIdx.x, lane = tid & 63, wv = tid >> 6;
    int lpx = lane & 15, lk = lane >> 4;
    int co0 = wv * 32;

    __shared__ ushort ft[16 * 198 * 8];     // [chunk][row*66+col][8]  (50,688 B)

    const long long ibase = (long long)(b << 14);

    for (int i = tid; i < 16 * 198; i += BLK) {
        int chunk = i / 198;
        int rem = i - chunk * 198;
        int row = rem / 66, col = rem - row * 66;
        int gh = h0 + row - 1, gw = w0 + col - 1;
        uint4 v = make_uint4(0, 0, 0, 0);
        if ((unsigned)gh < 128u && (unsigned)gw < 128u)
            v = *reinterpret_cast<const uint4*>(
                &fT[((ibase + (gh << 7) + gw) << 7) + (chunk << 3)]);
        *reinterpret_cast<uint4*>(&ft[i << 3]) = v;
    }
    __syncthreads();

    f32x4 acc[2][4];
    #pragma unroll
    for (int f = 0; f < 2; ++f)
        #pragma unroll
        for (int p = 0; p < 4; ++p) acc[f][p] = f32x4{0.f, 0.f, 0.f, 0.f};

    for (int tap = 0; tap < 9; ++tap) {
        int ki = tap / 3, kj = tap - ki * 3;
        const ushort* wtp = &wA[tap << 14];
        short8 a[2][4];
        #pragma unroll
        for (int f = 0; f < 2; ++f) {
            int co = co0 + f * 16 + lpx;
            #pragma unroll
            for (int q = 0; q < 4; ++q)
                a[f][q] = *reinterpret_cast<const short8*>(
                    &wtp[(((q * 4 + lk) << 7) + co) << 3]);
        }
        #pragma unroll
        for (int p = 0; p < 4; ++p) {
            int col = p * 16 + lpx + kj;           // 0..65
            short8 bq[4];
            #pragma unroll
            for (int q = 0; q < 4; ++q)
                bq[q] = *reinterpret_cast<const short8*>(
                    &ft[((q * 4 + lk) * 198 + ki * 66 + col) << 3]);
            #pragma unroll
            for (int f = 0; f < 2; ++f)
                #pragma unroll
                for (int q = 0; q < 4; ++q)
                    acc[f][p] = __builtin_amdgcn_mfma_f32_16x16x32_bf16(
                        a[f][q], bq[q], acc[f][p], 0, 0, 0);
        }
    }

    long long obase = (ibase + ((long long)h0 << 7)) << 7;
    #pragma unroll
    for (int f = 0; f < 2; ++f)
        #pragma unroll
        for (int p = 0; p < 4; ++p) {
            int c  = co0 + f * 16 + (lk << 2);
            int px = w0 + p * 16 + lpx;
            float v0 = fmaxf(acc[f][p][0], 0.f), v1 = fmaxf(acc[f][p][1], 0.f);
            float v2 = fmaxf(acc[f][p][2], 0.f), v3 = fmaxf(acc[f][p][3], 0.f);
            ushort* dst = &hT[obase + ((long long)px << 7) + c];
            *reinterpret_cast<uint*>(&dst[0]) = pack2(v0, v1);
            *reinterpret_cast<uint*>(&dst[2]) = pack2(v2, v3);
        }
}

// ---------------------------------------------------------------------------
// Fused dynamic-filter v15 = v14 structure (1-row blocks, 64 KB LDS, proven
// bit-identical in R14) with the launch bound relaxed (512,4)->(512,2): the
// (512,4) bound capped VGPRs at 64 and spilled to scratch (444 MB fetch!).
// With ~128 VGPR live set intact: 2 blocks/CU via LDS, no spill.
// ---------------------------------------------------------------------------
__global__ __launch_bounds__(512, 2) void k_dfapply(
    const ushort* __restrict__ hTr, const ushort* __restrict__ hTe,
    const ushort* __restrict__ fTr, const ushort* __restrict__ fTe,
    const ushort* __restrict__ w2b,
    ushort* __restrict__ enhr, ushort* __restrict__ enhe)
{
    int bid = blockIdx.x;           // 2s * 2b * 128 rows = 512
    int s = bid >> 8, b = (bid >> 7) & 1, h0 = bid & 127;
    const ushort* hT = s ? hTe : hTr;
    const ushort* fT = s ? fTe : fTr;
    ushort* enh = s ? enhe : enhr;
    int tid = threadIdx.x, lane = tid & 63, wv = tid >> 6;
    int lpx = lane & 15, lk = lane >> 4;
    int co0 = (wv & 1) * 64, px0 = (wv >> 1) * 32;

    __shared__ ushort wk[16 * 128 * 8];      // 32 KB weights (single buffer)
    __shared__ ushort fr[128 * 16 * 8];      // 32 KB feat row (swizzled)

    const long long ibase = (long long)(b << 14);
    const long long rowbase = (ibase + ((long long)h0 << 7)) << 7;

    // persistent B fragments (h tile, 32px x 128ci) from global (L2)
    short8 bq[2][4];
    #pragma unroll
    for (int p = 0; p < 2; ++p) {
        int px = px0 + p * 16 + lpx;
        #pragma unroll
        for (int q = 0; q < 4; ++q)
            bq[p][q] = *reinterpret_cast<const short8*>(
                &hT[rowbase + ((long long)px << 7) + ((q * 4 + lk) << 3)]);
    }

    // stage feat row h0+dh into fr (pre-swizzled source: su = u ^ (px&15))
    auto stage_row = [&](int dh) {
        int gh = h0 + dh;
        if ((unsigned)gh < 128u) {
            const ushort* rowsrc = fT + ((ibase + ((long long)gh << 7)) << 7);
            #pragma unroll
            for (int t = 0; t < 4; ++t) {
                int j = tid + (t << 9);          // 0..2047
                int px = j >> 4, u = j & 15;
                int su = u ^ (px & 15);
                gload16(&rowsrc[(px << 7) + (su << 3)], &fr[j << 3]);
            }
        }
    };

    // prologue: weights for k=0 + row for dh=-2
    #pragma unroll
    for (int t = 0; t < 4; ++t) {
        int j = tid + (t << 9);
        gload16(&w2b[j << 3], &wk[j << 3]);
    }
    stage_row(-2);
    __syncthreads();

    f32x4 osum[4][2];
    #pragma unroll
    for (int f = 0; f < 4; ++f)
        #pragma unroll
        for (int p = 0; p < 2; ++p) osum[f][p] = f32x4{0.f, 0.f, 0.f, 0.f};

    for (int k = 0; k < 25; ++k) {
        int k5 = k / 5;
        int dh = k5 - 2, dw = k - k5 * 5 - 2;
        int gh = h0 + dh;
        bool rowok = (unsigned)gh < 128u;

        uint2 featv[2][4];
        #pragma unroll
        for (int p = 0; p < 2; ++p) {
            int gw = px0 + p * 16 + lpx + dw;
            bool ok = rowok && ((unsigned)gw < 128u);
            #pragma unroll
            for (int f = 0; f < 4; ++f) {
                int c4 = co0 + f * 16 + (lk << 2);
                uint2 v = make_uint2(0, 0);
                if (ok) v = *reinterpret_cast<const uint2*>(
                    &fr[(((gw << 4) + ((c4 >> 3) ^ (gw & 15))) << 3)
                        + (c4 & 7)]);
                featv[p][f] = v;
            }
        }

        #pragma unroll
        for (int f = 0; f < 4; ++f) {
            int co = co0 + f * 16 + lpx;
            short8 a[4];
            #pragma unroll
            for (int q = 0; q < 4; ++q)
                a[q] = *reinterpret_cast<const short8*>(
                    &wk[(((q * 4 + lk) << 7) + co) << 3]);
            __builtin_amdgcn_s_setprio(1);
            #pragma unroll
            for (int p = 0; p < 2; ++p) {
                f32x4 fac = f32x4{0.f, 0.f, 0.f, 0.f};
                #pragma unroll
                for (int q = 0; q < 4; ++q)
                    fac = __builtin_amdgcn_mfma_f32_16x16x32_bf16(
                        a[q], bq[p][q], fac, 0, 0, 0);
                uint2 fv = featv[p][f];
                osum[f][p][0] += fac[0] * bf2f((ushort)(fv.x & 0xffff));
                osum[f][p][1] += fac[1] * bf2f((ushort)(fv.x >> 16));
                osum[f][p][2] += fac[2] * bf2f((ushort)(fv.y & 0xffff));
                osum[f][p][3] += fac[3] * bf2f((ushort)(fv.y >> 16));
            }
            __builtin_amdgcn_s_setprio(0);
        }
        __syncthreads();             // all reads of wk/fr done
        if (k < 24) {
            const ushort* srcb = &w2b[(k + 1) << 14];
            #pragma unroll
            for (int t = 0; t < 4; ++t) {
                int j = tid + (t << 9);
                gload16(&srcb[j << 3], &wk[j << 3]);
            }
            if (k - k5 * 5 == 4)     // group boundary: next dh's row
                stage_row(k5 - 1);   // dh_next = (k+1)/5 - 2 = k5 - 1
            __syncthreads();         // DMA landed (vmcnt drained)
        }
    }

    // park osum in fr at [px][chunk ^ (px&15)][8] (bf16, same values)
    #pragma unroll
    for (int f = 0; f < 4; ++f)
        #pragma unroll
        for (int p = 0; p < 2; ++p) {
            int c  = co0 + f * 16 + (lk << 2);
            int px = px0 + p * 16 + lpx;
            int slot = (c >> 3) ^ (px & 15);
            uint2 o;
            o.x = pack2(osum[f][p][0], osum[f][p][1]);
            o.y = pack2(osum[f][p][2], osum[f][p][3]);
            *reinterpret_cast<uint2*>(
                &fr[(((px << 4) + slot) << 3) + (c & 7)]) = o;
        }
    __syncthreads();

    // coalesced enh stores: per 16-lane group one px's 256B window
    #pragma unroll
    for (int t = 0; t < 4; ++t) {
        int j  = tid + (t << 9);          // 0..2047
        int px = j >> 4, u = j & 15;
        int chunk = u ^ (px & 15);
        uint4 v = *reinterpret_cast<const uint4*>(&fr[j << 3]);
        *reinterpret_cast<uint4*>(
            &enh[rowbase + ((long long)px << 7) + (chunk << 3)]) = v;
    }
}

// ---------------------------------------------------------------------------
// Tail — exact R10..R13 version (proven).
// ---------------------------------------------------------------------------
__global__ __launch_bounds__(BLK, 2) void k_final(
    const ushort* __restrict__ enhr, const ushort* __restrict__ enhe,
    const float* __restrict__ featrT,
    const ushort* __restrict__ wspb, const float* __restrict__ w_out,
    const float* __restrict__ lng, const float* __restrict__ lnb,
    float* __restrict__ out)
{
    int bid = blockIdx.x;            // Bb * 256
    int b = bid >> 8;
    int px0g = (bid & 255) * 64;
    int tid = threadIdx.x, lane = tid & 63, wv = tid >> 6;
    int lpx = lane & 15, lk = lane >> 4;

    __shared__ float woA[4096];
    __shared__ float woB[4096];
    __shared__ float xs[128][64];
    __shared__ float p1[4][64], p2[4][64];
    ushort* es = (ushort*)woA;

    const long long ebase = ((long long)((b << 14) + px0g)) << 7;

    #pragma unroll
    for (int t = 0; t < 4; ++t) {
        int j = tid + (t << 8);
        int chunk = j >> 6, px = j & 63;
        *reinterpret_cast<uint4*>(&es[j << 3]) =
            *reinterpret_cast<const uint4*>(
                &enhe[ebase + ((long long)px << 7) + (chunk << 3)]);
    }
    __syncthreads();

    int co0 = wv * 32;
    f32x4 sp[2][4];
    #pragma unroll
    for (int f = 0; f < 2; ++f)
        #pragma unroll
        for (int p = 0; p < 4; ++p) sp[f][p] = f32x4{0.f, 0.f, 0.f, 0.f};
    #pragma unroll
    for (int q = 0; q < 4; ++q) {
        short8 a[2], bb[4];
        #pragma unroll
        for (int f = 0; f < 2; ++f)
            a[f] = *reinterpret_cast<const short8*>(
                &wspb[((((q * 4 + lk) << 7) + co0 + f * 16 + lpx)) << 3]);
        #pragma unroll
        for (int p = 0; p < 4; ++p)
            bb[p] = *reinterpret_cast<const short8*>(
                &es[((((q * 4 + lk) << 6) + p * 16 + lpx)) << 3]);
        #pragma unroll
        for (int f = 0; f < 2; ++f)
            #pragma unroll
            for (int p = 0; p < 4; ++p)
                sp[f][p] = __builtin_amdgcn_mfma_f32_16x16x32_bf16(
                    a[f], bb[p], sp[f][p], 0, 0, 0);
    }

    float fu[2][4][4];
    float s1[4] = {0.f, 0.f, 0.f, 0.f}, s2[4] = {0.f, 0.f, 0.f, 0.f};
    #pragma unroll
    for (int f = 0; f < 2; ++f) {
        int c4 = co0 + f * 16 + (lk << 2);
        #pragma unroll
        for (int p = 0; p < 4; ++p) {
            int px = p * 16 + lpx;
            long long poff = ebase + ((long long)px << 7) + c4;
            uint2 re2 = *reinterpret_cast<const uint2*>(&enhr[poff]);
            float4 rf4 = *reinterpret_cast<const float4*>(&featrT[poff]);
            float re[4] = { bf2f((ushort)(re2.x & 0xffff)), bf2f((ushort)(re2.x >> 16)),
                            bf2f((ushort)(re2.y & 0xffff)), bf2f((ushort)(re2.y >> 16)) };
            float rf[4] = { rf4.x, rf4.y, rf4.z, rf4.w };
            #pragma unroll
            for (int rr = 0; rr < 4; ++rr) {
                float sg = 1.f / (1.f + __expf(-sp[f][p][rr]));
                float v = re[rr] * (1.f + sg) + rf[rr];
                fu[f][p][rr] = v;
                s1[p] += v; s2[p] += v * v;
            }
        }
    }
    #pragma unroll
    for (int p = 0; p < 4; ++p) {
        s1[p] += __shfl_xor(s1[p], 16); s1[p] += __shfl_xor(s1[p], 32);
        s2[p] += __shfl_xor(s2[p], 16); s2[p] += __shfl_xor(s2[p], 32);
    }
    if (lk == 0) {
        #pragma unroll
        for (int p = 0; p < 4; ++p) {
            p1[wv][p * 16 + lpx] = s1[p];
            p2[wv][p * 16 + lpx] = s2[p];
        }
    }
    __syncthreads();

    #pragma unroll
    for (int i = 0; i < 8; ++i) {
        int fidx = tid + (i << 8);
        float4 v = *reinterpret_cast<const float4*>(&w_out[fidx << 2]);
        if (fidx < 1024) reinterpret_cast<float4*>(woA)[fidx] = v;
        else             reinterpret_cast<float4*>(woB)[fidx - 1024] = v;
    }

    float mm[4], rs[4];
    #pragma unroll
    for (int p = 0; p < 4; ++p) {
        int px = p * 16 + lpx;
        float m   = (p1[0][px] + p1[1][px] + p1[2][px] + p1[3][px]) * (1.f / 128.f);
        float ex2 = (p2[0][px] + p2[1][px] + p2[2][px] + p2[3][px]) * (1.f / 128.f);
        mm[p] = m;
        rs[p] = rsqrtf(ex2 - m * m + EPSV);
    }

    #pragma unroll
    for (int f = 0; f < 2; ++f) {
        int c4 = co0 + f * 16 + (lk << 2);
        float4 g = *reinterpret_cast<const float4*>(&lng[c4]);
        float4 bta = *reinterpret_cast<const float4*>(&lnb[c4]);
        #pragma unroll
        for (int p = 0; p < 4; ++p) {
            int px = p * 16 + lpx;
            xs[c4 + 0][px] = (fu[f][p][0] - mm[p]) * rs[p] * g.x + bta.x;
            xs[c4 + 1][px] = (fu[f][p][1] - mm[p]) * rs[p] * g.y + bta.y;
            xs[c4 + 2][px] = (fu[f][p][2] - mm[p]) * rs[p] * g.z + bta.z;
            xs[c4 + 3][px] = (fu[f][p][3] - mm[p]) * rs[p] * g.w + bta.w;
        }
    }
    __syncthreads();

    int co0o = wv * 16;
    const float* wop = (wv & 2) ? woB : woA;
    int wbase = (wv & 1) << 11;
    float oacc[16];
    #pragma unroll
    for (int oo = 0; oo < 16; ++oo) oacc[oo] = 0.f;
    for (int j4 = 0; j4 < 32; ++j4) {
        float x0 = xs[j4 * 4 + 0][lane];
        float x1 = xs[j4 * 4 + 1][lane];
        float x2 = xs[j4 * 4 + 2][lane];
        float x3 = xs[j4 * 4 + 3][lane];
        #pragma unroll
        for (int oo = 0; oo < 16; ++oo) {
            float4 wv4 = *reinterpret_cast<const float4*>(
                &wop[wbase + oo * C_Hc + j4 * 4]);
            oacc[oo] += wv4.x * x0 + wv4.y * x1 + wv4.z * x2 + wv4.w * x3;
        }
    }
    #pragma unroll
    for (int oo = 0; oo < 16; ++oo)
        out[((long long)(b * C_INc + co0o + oo) << 14) + px0g + lane] = oacc[oo];
}

// ---------------------------------------------------------------------------
extern "C" void kernel_launch(void* const* d_in, const int* in_sizes, int n_in,
                              void* d_out, int out_size, void* d_ws, size_t ws_size,
                              hipStream_t stream)
{
    const float* rgb  = (const float*)d_in[0];
    const float* evt  = (const float*)d_in[1];
    const float* w_in = (const float*)d_in[2];
    const float* lng  = (const float*)d_in[3];
    const float* lnb  = (const float*)d_in[4];
    const float* w1   = (const float*)d_in[5];
    const float* w2   = (const float*)d_in[6];
    const float* wsp  = (const float*)d_in[7];
    const float* wout = (const float*)d_in[8];
    float* out = (float*)d_out;

    float* ws = (float*)d_ws;
    ushort* fTr    = (ushort*)(ws);
    ushort* fTe    = (ushort*)(ws + 2097152);
    ushort* hTr    = (ushort*)(ws + 4194304);
    ushort* hTe    = (ushort*)(ws + 6291456);
    ushort* enhr   = (ushort*)(ws + 8388608);
    ushort* enhe   = (ushort*)(ws + 10485760);
    float*  featrT = (float*)(ws + 12582912);   // 4,194,304 f (fp32 NHWC, rgb)
    ushort* wA     = (ushort*)(ws + 16777216);  // 147456 bf16
    ushort* w2b    = (ushort*)(ws + 16850944);  // 409600 bf16
    ushort* wspb   = (ushort*)(ws + 17055744);  // 16384 bf16

    k_prep<<<2240, BLK, 0, stream>>>(w1, w2, wsp, wA, w2b, wspb);
    k_in_ln<<<2 * Bb * 256, BLK, 0, stream>>>(rgb, evt, w_in, lng, lnb,
                                              fTr, fTe, featrT);
    k_conv3<<<1024, BLK, 0, stream>>>(fTr, fTe, wA, hTr, hTe);
    k_dfapply<<<512, 512, 0, stream>>>(hTr, hTe, fTr, fTe, w2b, enhr, enhe);
    k_final<<<Bb * 256, BLK, 0, stream>>>(enhr, enhe, featrT, wspb, wout,
                                          lng, lnb, out);
}

// Round 16
// 199.851 us; speedup vs baseline: 1.5590x; 1.0672x over previous
//
#include <hip/hip_runtime.h>
#include <math.h>

#define BLK 256

typedef unsigned short ushort;
typedef unsigned int uint;
typedef __attribute__((ext_vector_type(8))) short short8;
typedef __attribute__((ext_vector_type(4))) float f32x4;

constexpr int C_Hc = 128;
constexpr int C_INc = 64;
constexpr int Hh = 128;
constexpr int Ww = 128;
constexpr int HWc = Hh * Ww;   // 16384
constexpr int Bb = 2;
constexpr float EPSV = 1e-5f;

__device__ __forceinline__ float bf2f(ushort u) {
    union { uint u32; float f; } v; v.u32 = (uint)u << 16; return v.f;
}
__device__ __forceinline__ ushort f2bf(float x) {
    union { float f; uint u; } v; v.f = x;
    uint r = (v.u + 0x7FFFu + ((v.u >> 16) & 1u)) >> 16;
    return (ushort)r;
}
__device__ __forceinline__ uint pack2(float a, float b) {
    return (uint)f2bf(a) | ((uint)f2bf(b) << 16);
}
__device__ __forceinline__ void gload16(const ushort* g, ushort* l) {
    __builtin_amdgcn_global_load_lds(
        (const __attribute__((address_space(1))) void*)g,
        (__attribute__((address_space(3))) void*)l, 16, 0, 0);
}

// ---------------------------------------------------------------------------
// Weight prep (chunk-major bf16) — exact R5/R9 version.
// ---------------------------------------------------------------------------
__global__ __launch_bounds__(BLK) void k_prep(
    const float* __restrict__ w1, const float* __restrict__ w2,
    const float* __restrict__ wsp,
    ushort* __restrict__ wA, ushort* __restrict__ w2b,
    ushort* __restrict__ wspb)
{
    int idx = blockIdx.x * BLK + threadIdx.x;
    if (idx < 147456) {                       // wA: 9 * 16384
        int tap = idx >> 14, r = idx & 16383;
        int chunk = r >> 10, co = (r >> 3) & 127, e = r & 7;
        int ci = chunk * 8 + e;
        wA[idx] = f2bf(w1[(co * 128 + ci) * 9 + tap]);
    } else if (idx < 557056) {                // w2b: 25 * 16384
        int o = idx - 147456;
        int k = o >> 14, r = o & 16383;
        int chunk = r >> 10, co = (r >> 3) & 127, e = r & 7;
        int ci = chunk * 8 + e;
        w2b[o] = f2bf(w2[(co * 25 + k) * 128 + ci]);
    } else if (idx < 573440) {                // wspb: 16384
        int o = idx - 557056;
        int chunk = o >> 10, co = (o >> 3) & 127, e = o & 7;
        wspb[o] = f2bf(wsp[co * 128 + chunk * 8 + e]);
    }
}

// ---------------------------------------------------------------------------
// conv1x1(w_in) + LayerNorm — exact R11/R12 version (LDS-transposed stores).
// ---------------------------------------------------------------------------
__global__ __launch_bounds__(BLK) void k_in_ln(
    const float* __restrict__ xr, const float* __restrict__ xe,
    const float* __restrict__ w_in, const float* __restrict__ lng,
    const float* __restrict__ lnb,
    ushort* __restrict__ fTr, ushort* __restrict__ fTe,
    float* __restrict__ featrT)
{
    int bid  = blockIdx.x;          // 2 * Bb * 256
    int simg = bid >> 9;
    int rem  = bid & 511;
    int b    = rem >> 8;
    int base = (rem & 255) * 64;
    const float* x = simg ? xe : xr;
    ushort* fT = simg ? fTe : fTr;
    int tid  = threadIdx.x;
    int lane = tid & 63;
    int cg   = tid >> 6;

    __shared__ float xs[C_INc][64];
    __shared__ float r1[4][64], r2[4][64];
    __shared__ ushort lb[64][136];     // bf16 [px][ch] transpose, padded row
    __shared__ float  lf[64][132];     // fp32 [px][ch] transpose, padded row

    #pragma unroll
    for (int r = 0; r < 16; ++r) {
        int i = cg * 16 + r;
        xs[i][lane] = x[(b * C_INc + i) * HWc + base + lane];
    }
    __syncthreads();

    float acc[32];
    #pragma unroll
    for (int cc = 0; cc < 32; ++cc) acc[cc] = 0.f;

    for (int i4 = 0; i4 < 16; ++i4) {
        float x0 = xs[i4 * 4 + 0][lane];
        float x1 = xs[i4 * 4 + 1][lane];
        float x2 = xs[i4 * 4 + 2][lane];
        float x3 = xs[i4 * 4 + 3][lane];
        #pragma unroll
        for (int cc = 0; cc < 32; ++cc) {
            float4 wv = *reinterpret_cast<const float4*>(
                &w_in[(cg * 32 + cc) * C_INc + i4 * 4]);
            acc[cc] += wv.x * x0 + wv.y * x1 + wv.z * x2 + wv.w * x3;
        }
    }

    float s1 = 0.f, s2 = 0.f;
    #pragma unroll
    for (int cc = 0; cc < 32; ++cc) { s1 += acc[cc]; s2 += acc[cc] * acc[cc]; }
    r1[cg][lane] = s1; r2[cg][lane] = s2;
    __syncthreads();
    float m   = (r1[0][lane] + r1[1][lane] + r1[2][lane] + r1[3][lane]) * (1.f / C_Hc);
    float ex2 = (r2[0][lane] + r2[1][lane] + r2[2][lane] + r2[3][lane]) * (1.f / C_Hc);
    float rs  = rsqrtf(ex2 - m * m + EPSV);

    #pragma unroll
    for (int cc = 0; cc < 32; cc += 4) {
        int c0 = cg * 32 + cc;
        float4 g4 = *reinterpret_cast<const float4*>(&lng[c0]);
        float4 b4 = *reinterpret_cast<const float4*>(&lnb[c0]);
        float4 y;
        y.x = (acc[cc + 0] - m) * rs * g4.x + b4.x;
        y.y = (acc[cc + 1] - m) * rs * g4.y + b4.y;
        y.z = (acc[cc + 2] - m) * rs * g4.z + b4.z;
        y.w = (acc[cc + 3] - m) * rs * g4.w + b4.w;
        *reinterpret_cast<uint*>(&lb[lane][c0])     = pack2(y.x, y.y);
        *reinterpret_cast<uint*>(&lb[lane][c0 + 2]) = pack2(y.z, y.w);
        if (!simg)
            *reinterpret_cast<float4*>(&lf[lane][c0]) = y;
    }
    __syncthreads();

    long long tb = ((long long)((b << 14) + base)) << 7;   // ushort index
    #pragma unroll
    for (int t = 0; t < 4; ++t) {
        int j  = tid + (t << 8);          // 0..1023
        int px = j >> 4;                  // 0..63
        int w0 = (j & 15) << 3;           // ushort offset 0..120
        uint4 v = *reinterpret_cast<const uint4*>(&lb[px][w0]);
        *reinterpret_cast<uint4*>(&fT[tb + ((long long)px << 7) + w0]) = v;
    }
    if (!simg) {
        #pragma unroll
        for (int t = 0; t < 8; ++t) {
            int j  = tid + (t << 8);      // 0..2047
            int px = j >> 5;              // 0..63
            int w0 = (j & 31) << 2;       // float offset 0..124
            float4 v = *reinterpret_cast<const float4*>(&lf[px][w0]);
            *reinterpret_cast<float4*>(&featrT[tb + ((long long)px << 7) + w0]) = v;
        }
    }
}

// ---------------------------------------------------------------------------
// conv3x3 + ReLU — exact R13 half-row version (proven bit-identical).
// ---------------------------------------------------------------------------
__global__ __launch_bounds__(BLK, 3) void k_conv3(
    const ushort* __restrict__ fTr, const ushort* __restrict__ fTe,
    const ushort* __restrict__ wA,
    ushort* __restrict__ hTr, ushort* __restrict__ hTe)
{
    int bid = blockIdx.x;           // 2s * 2b * 128 rows * 2 halves = 1024
    int ph = bid & 1, h0 = (bid >> 1) & 127, b = (bid >> 8) & 1, s = bid >> 9;
    int w0 = ph << 6;
    const ushort* fT = s ? fTe : fTr;
    ushort* hT = s ? hTe : hTr;
    int tid = threadIdx.x, lane = tid & 63, wv = tid >> 6;
    int lpx = lane & 15, lk = lane >> 4;
    int co0 = wv * 32;

    __shared__ ushort ft[16 * 198 * 8];     // [chunk][row*66+col][8]  (50,688 B)

    const long long ibase = (long long)(b << 14);

    for (int i = tid; i < 16 * 198; i += BLK) {
        int chunk = i / 198;
        int rem = i - chunk * 198;
        int row = rem / 66, col = rem - row * 66;
        int gh = h0 + row - 1, gw = w0 + col - 1;
        uint4 v = make_uint4(0, 0, 0, 0);
        if ((unsigned)gh < 128u && (unsigned)gw < 128u)
            v = *reinterpret_cast<const uint4*>(
                &fT[((ibase + (gh << 7) + gw) << 7) + (chunk << 3)]);
        *reinterpret_cast<uint4*>(&ft[i << 3]) = v;
    }
    __syncthreads();

    f32x4 acc[2][4];
    #pragma unroll
    for (int f = 0; f < 2; ++f)
        #pragma unroll
        for (int p = 0; p < 4; ++p) acc[f][p] = f32x4{0.f, 0.f, 0.f, 0.f};

    for (int tap = 0; tap < 9; ++tap) {
        int ki = tap / 3, kj = tap - ki * 3;
        const ushort* wtp = &wA[tap << 14];
        short8 a[2][4];
        #pragma unroll
        for (int f = 0; f < 2; ++f) {
            int co = co0 + f * 16 + lpx;
            #pragma unroll
            for (int q = 0; q < 4; ++q)
                a[f][q] = *reinterpret_cast<const short8*>(
                    &wtp[(((q * 4 + lk) << 7) + co) << 3]);
        }
        #pragma unroll
        for (int p = 0; p < 4; ++p) {
            int col = p * 16 + lpx + kj;           // 0..65
            short8 bq[4];
            #pragma unroll
            for (int q = 0; q < 4; ++q)
                bq[q] = *reinterpret_cast<const short8*>(
                    &ft[((q * 4 + lk) * 198 + ki * 66 + col) << 3]);
            #pragma unroll
            for (int f = 0; f < 2; ++f)
                #pragma unroll
                for (int q = 0; q < 4; ++q)
                    acc[f][p] = __builtin_amdgcn_mfma_f32_16x16x32_bf16(
                        a[f][q], bq[q], acc[f][p], 0, 0, 0);
        }
    }

    long long obase = (ibase + ((long long)h0 << 7)) << 7;
    #pragma unroll
    for (int f = 0; f < 2; ++f)
        #pragma unroll
        for (int p = 0; p < 4; ++p) {
            int c  = co0 + f * 16 + (lk << 2);
            int px = w0 + p * 16 + lpx;
            float v0 = fmaxf(acc[f][p][0], 0.f), v1 = fmaxf(acc[f][p][1], 0.f);
            float v2 = fmaxf(acc[f][p][2], 0.f), v3 = fmaxf(acc[f][p][3], 0.f);
            ushort* dst = &hT[obase + ((long long)px << 7) + c];
            *reinterpret_cast<uint*>(&dst[0]) = pack2(v0, v1);
            *reinterpret_cast<uint*>(&dst[2]) = pack2(v2, v3);
        }
}

// ---------------------------------------------------------------------------
// Fused dynamic-filter — exact R12/R13 version (proven best: ~82 us,
// absmax 0.015625).  Block = 2 rows (512 thr, 8 waves), wave 64co x 64px;
// wk DMA double-buffered; fr per-group row staging, swizzle u^(px&15);
// enh stores transposed through dead fr.
// ---------------------------------------------------------------------------
__global__ __launch_bounds__(512, 2) void k_dfapply(
    const ushort* __restrict__ hTr, const ushort* __restrict__ hTe,
    const ushort* __restrict__ fTr, const ushort* __restrict__ fTe,
    const ushort* __restrict__ w2b,
    ushort* __restrict__ enhr, ushort* __restrict__ enhe)
{
    int bid = blockIdx.x;           // 2s * 2b * 64 row-pairs = 256
    int s = bid >> 7, b = (bid >> 6) & 1, hp = bid & 63;
    int h0g = hp << 1;
    const ushort* hT = s ? hTe : hTr;
    const ushort* fT = s ? fTe : fTr;
    ushort* enh = s ? enhe : enhr;
    int tid = threadIdx.x, lane = tid & 63, wv = tid >> 6;
    int lpx = lane & 15, lk = lane >> 4;
    int r    = wv >> 2;                      // wave's row within pair
    int co0  = (wv & 1) * 64, px0 = ((wv >> 1) & 1) * 64;
    int h0   = h0g + r;

    __shared__ ushort wk[2][16 * 128 * 8];   // 2 x 32 KB weights
    __shared__ ushort fr[2][128 * 16 * 8];   // 2 rows x 32 KB feat (swizzled)

    const long long ibase = (long long)(b << 14);
    const long long rowbase = (ibase + ((long long)h0 << 7)) << 7;

    short8 bq[4][4];
    #pragma unroll
    for (int p = 0; p < 4; ++p) {
        int px = px0 + p * 16 + lpx;
        #pragma unroll
        for (int q = 0; q < 4; ++q)
            bq[p][q] = *reinterpret_cast<const short8*>(
                &hT[rowbase + ((long long)px << 7) + ((q * 4 + lk) << 3)]);
    }

    auto stage_rows = [&](int dh) {
        for (int rr = 0; rr < 2; ++rr) {
            int gh = h0g + rr + dh;
            if ((unsigned)gh < 128u) {
                const ushort* rowsrc = fT + ((ibase + ((long long)gh << 7)) << 7);
                #pragma unroll
                for (int t = 0; t < 4; ++t) {
                    int j = tid + (t << 9);          // 0..2047
                    int px = j >> 4, u = j & 15;
                    int su = u ^ (px & 15);
                    gload16(&rowsrc[(px << 7) + (su << 3)], &fr[rr][j << 3]);
                }
            }
        }
    };

    #pragma unroll
    for (int t = 0; t < 4; ++t) {
        int j = tid + (t << 9);
        gload16(&w2b[j << 3], &wk[0][j << 3]);
    }
    stage_rows(-2);
    __syncthreads();

    f32x4 osum[4][4];
    #pragma unroll
    for (int f = 0; f < 4; ++f)
        #pragma unroll
        for (int p = 0; p < 4; ++p) osum[f][p] = f32x4{0.f, 0.f, 0.f, 0.f};

    for (int k = 0; k < 25; ++k) {
        int cur = k & 1;
        if (k < 24) {
            const ushort* srcb = &w2b[(k + 1) << 14];
            #pragma unroll
            for (int t = 0; t < 4; ++t) {
                int j = tid + (t << 9);
                gload16(&srcb[j << 3], &wk[cur ^ 1][j << 3]);
            }
        }
        int k5 = k / 5;
        int dh = k5 - 2, dw = k - k5 * 5 - 2;
        int gh = h0 + dh;
        bool rowok = (unsigned)gh < 128u;

        uint2 featv[4][4];
        #pragma unroll
        for (int p = 0; p < 4; ++p) {
            int gw = px0 + p * 16 + lpx + dw;
            bool ok = rowok && ((unsigned)gw < 128u);
            #pragma unroll
            for (int f = 0; f < 4; ++f) {
                int c4 = co0 + f * 16 + (lk << 2);
                uint2 v = make_uint2(0, 0);
                if (ok) v = *reinterpret_cast<const uint2*>(
                    &fr[r][(((gw << 4) + ((c4 >> 3) ^ (gw & 15))) << 3)
                           + (c4 & 7)]);
                featv[p][f] = v;
            }
        }

        #pragma unroll
        for (int f = 0; f < 4; ++f) {
            int co = co0 + f * 16 + lpx;
            short8 a[4];
            #pragma unroll
            for (int q = 0; q < 4; ++q)
                a[q] = *reinterpret_cast<const short8*>(
                    &wk[cur][(((q * 4 + lk) << 7) + co) << 3]);
            __builtin_amdgcn_s_setprio(1);
            #pragma unroll
            for (int p = 0; p < 4; ++p) {
                f32x4 fac = f32x4{0.f, 0.f, 0.f, 0.f};
                #pragma unroll
                for (int q = 0; q < 4; ++q)
                    fac = __builtin_amdgcn_mfma_f32_16x16x32_bf16(
                        a[q], bq[p][q], fac, 0, 0, 0);
                uint2 fv = featv[p][f];
                osum[f][p][0] += fac[0] * bf2f((ushort)(fv.x & 0xffff));
                osum[f][p][1] += fac[1] * bf2f((ushort)(fv.x >> 16));
                osum[f][p][2] += fac[2] * bf2f((ushort)(fv.y & 0xffff));
                osum[f][p][3] += fac[3] * bf2f((ushort)(fv.y >> 16));
            }
            __builtin_amdgcn_s_setprio(0);
        }
        __syncthreads();
        if ((k % 5 == 4) && k < 24) {
            stage_rows(k / 5 - 1);
            __syncthreads();
        }
    }

    // park osum in fr[r] at [px][chunk ^ (px&15)][8] (bf16, same values)
    #pragma unroll
    for (int f = 0; f < 4; ++f)
        #pragma unroll
        for (int p = 0; p < 4; ++p) {
            int c  = co0 + f * 16 + (lk << 2);
            int px = px0 + p * 16 + lpx;
            int slot = (c >> 3) ^ (px & 15);
            uint2 o;
            o.x = pack2(osum[f][p][0], osum[f][p][1]);
            o.y = pack2(osum[f][p][2], osum[f][p][3]);
            *reinterpret_cast<uint2*>(
                &fr[r][(((px << 4) + slot) << 3) + (c & 7)]) = o;
        }
    __syncthreads();

    // coalesced enh stores: per 16-lane group one px's 256B window
    #pragma unroll
    for (int t = 0; t < 8; ++t) {
        int j  = tid + (t << 9);          // 0..4095
        int rr = j >> 11;                 // row within pair
        int jj = j & 2047;
        int px = jj >> 4, u = jj & 15;
        int chunk = u ^ (px & 15);
        uint4 v = *reinterpret_cast<const uint4*>(&fr[rr][jj << 3]);
        *reinterpret_cast<uint4*>(
            &enh[((ibase + ((long long)(h0g + rr) << 7)) << 7)
                 + ((long long)px << 7) + (chunk << 3)]) = v;
    }
}

// ---------------------------------------------------------------------------
// Tail — exact R10..R13 version (proven).
// ---------------------------------------------------------------------------
__global__ __launch_bounds__(BLK, 2) void k_final(
    const ushort* __restrict__ enhr, const ushort* __restrict__ enhe,
    const float* __restrict__ featrT,
    const ushort* __restrict__ wspb, const float* __restrict__ w_out,
    const float* __restrict__ lng, const float* __restrict__ lnb,
    float* __restrict__ out)
{
    int bid = blockIdx.x;            // Bb * 256
    int b = bid >> 8;
    int px0g = (bid & 255) * 64;
    int tid = threadIdx.x, lane = tid & 63, wv = tid >> 6;
    int lpx = lane & 15, lk = lane >> 4;

    __shared__ float woA[4096];
    __shared__ float woB[4096];
    __shared__ float xs[128][64];
    __shared__ float p1[4][64], p2[4][64];
    ushort* es = (ushort*)woA;

    const long long ebase = ((long long)((b << 14) + px0g)) << 7;

    #pragma unroll
    for (int t = 0; t < 4; ++t) {
        int j = tid + (t << 8);
        int chunk = j >> 6, px = j & 63;
        *reinterpret_cast<uint4*>(&es[j << 3]) =
            *reinterpret_cast<const uint4*>(
                &enhe[ebase + ((long long)px << 7) + (chunk << 3)]);
    }
    __syncthreads();

    int co0 = wv * 32;
    f32x4 sp[2][4];
    #pragma unroll
    for (int f = 0; f < 2; ++f)
        #pragma unroll
        for (int p = 0; p < 4; ++p) sp[f][p] = f32x4{0.f, 0.f, 0.f, 0.f};
    #pragma unroll
    for (int q = 0; q < 4; ++q) {
        short8 a[2], bb[4];
        #pragma unroll
        for (int f = 0; f < 2; ++f)
            a[f] = *reinterpret_cast<const short8*>(
                &wspb[((((q * 4 + lk) << 7) + co0 + f * 16 + lpx)) << 3]);
        #pragma unroll
        for (int p = 0; p < 4; ++p)
            bb[p] = *reinterpret_cast<const short8*>(
                &es[((((q * 4 + lk) << 6) + p * 16 + lpx)) << 3]);
        #pragma unroll
        for (int f = 0; f < 2; ++f)
            #pragma unroll
            for (int p = 0; p < 4; ++p)
                sp[f][p] = __builtin_amdgcn_mfma_f32_16x16x32_bf16(
                    a[f], bb[p], sp[f][p], 0, 0, 0);
    }

    float fu[2][4][4];
    float s1[4] = {0.f, 0.f, 0.f, 0.f}, s2[4] = {0.f, 0.f, 0.f, 0.f};
    #pragma unroll
    for (int f = 0; f < 2; ++f) {
        int c4 = co0 + f * 16 + (lk << 2);
        #pragma unroll
        for (int p = 0; p < 4; ++p) {
            int px = p * 16 + lpx;
            long long poff = ebase + ((long long)px << 7) + c4;
            uint2 re2 = *reinterpret_cast<const uint2*>(&enhr[poff]);
            float4 rf4 = *reinterpret_cast<const float4*>(&featrT[poff]);
            float re[4] = { bf2f((ushort)(re2.x & 0xffff)), bf2f((ushort)(re2.x >> 16)),
                            bf2f((ushort)(re2.y & 0xffff)), bf2f((ushort)(re2.y >> 16)) };
            float rf[4] = { rf4.x, rf4.y, rf4.z, rf4.w };
            #pragma unroll
            for (int rr = 0; rr < 4; ++rr) {
                float sg = 1.f / (1.f + __expf(-sp[f][p][rr]));
                float v = re[rr] * (1.f + sg) + rf[rr];
                fu[f][p][rr] = v;
                s1[p] += v; s2[p] += v * v;
            }
        }
    }
    #pragma unroll
    for (int p = 0; p < 4; ++p) {
        s1[p] += __shfl_xor(s1[p], 16); s1[p] += __shfl_xor(s1[p], 32);
        s2[p] += __shfl_xor(s2[p], 16); s2[p] += __shfl_xor(s2[p], 32);
    }
    if (lk == 0) {
        #pragma unroll
        for (int p = 0; p < 4; ++p) {
            p1[wv][p * 16 + lpx] = s1[p];
            p2[wv][p * 16 + lpx] = s2[p];
        }
    }
    __syncthreads();

    #pragma unroll
    for (int i = 0; i < 8; ++i) {
        int fidx = tid + (i << 8);
        float4 v = *reinterpret_cast<const float4*>(&w_out[fidx << 2]);
        if (fidx < 1024) reinterpret_cast<float4*>(woA)[fidx] = v;
        else             reinterpret_cast<float4*>(woB)[fidx - 1024] = v;
    }

    float mm[4], rs[4];
    #pragma unroll
    for (int p = 0; p < 4; ++p) {
        int px = p * 16 + lpx;
        float m   = (p1[0][px] + p1[1][px] + p1[2][px] + p1[3][px]) * (1.f / 128.f);
        float ex2 = (p2[0][px] + p2[1][px] + p2[2][px] + p2[3][px]) * (1.f / 128.f);
        mm[p] = m;
        rs[p] = rsqrtf(ex2 - m * m + EPSV);
    }

    #pragma unroll
    for (int f = 0; f < 2; ++f) {
        int c4 = co0 + f * 16 + (lk << 2);
        float4 g = *reinterpret_cast<const float4*>(&lng[c4]);
        float4 bta = *reinterpret_cast<const float4*>(&lnb[c4]);
        #pragma unroll
        for (int p = 0; p < 4; ++p) {
            int px = p * 16 + lpx;
            xs[c4 + 0][px] = (fu[f][p][0] - mm[p]) * rs[p] * g.x + bta.x;
            xs[c4 + 1][px] = (fu[f][p][1] - mm[p]) * rs[p] * g.y + bta.y;
            xs[c4 + 2][px] = (fu[f][p][2] - mm[p]) * rs[p] * g.z + bta.z;
            xs[c4 + 3][px] = (fu[f][p][3] - mm[p]) * rs[p] * g.w + bta.w;
        }
    }
    __syncthreads();

    int co0o = wv * 16;
    const float* wop = (wv & 2) ? woB : woA;
    int wbase = (wv & 1) << 11;
    float oacc[16];
    #pragma unroll
    for (int oo = 0; oo < 16; ++oo) oacc[oo] = 0.f;
    for (int j4 = 0; j4 < 32; ++j4) {
        float x0 = xs[j4 * 4 + 0][lane];
        float x1 = xs[j4 * 4 + 1][lane];
        float x2 = xs[j4 * 4 + 2][lane];
        float x3 = xs[j4 * 4 + 3][lane];
        #pragma unroll
        for (int oo = 0; oo < 16; ++oo) {
            float4 wv4 = *reinterpret_cast<const float4*>(
                &wop[wbase + oo * C_Hc + j4 * 4]);
            oacc[oo] += wv4.x * x0 + wv4.y * x1 + wv4.z * x2 + wv4.w * x3;
        }
    }
    #pragma unroll
    for (int oo = 0; oo < 16; ++oo)
        out[((long long)(b * C_INc + co0o + oo) << 14) + px0g + lane] = oacc[oo];
}

// ---------------------------------------------------------------------------
extern "C" void kernel_launch(void* const* d_in, const int* in_sizes, int n_in,
                              void* d_out, int out_size, void* d_ws, size_t ws_size,
                              hipStream_t stream)
{
    const float* rgb  = (const float*)d_in[0];
    const float* evt  = (const float*)d_in[1];
    const float* w_in = (const float*)d_in[2];
    const float* lng  = (const float*)d_in[3];
    const float* lnb  = (const float*)d_in[4];
    const float* w1   = (const float*)d_in[5];
    const float* w2   = (const float*)d_in[6];
    const float* wsp  = (const float*)d_in[7];
    const float* wout = (const float*)d_in[8];
    float* out = (float*)d_out;

    float* ws = (float*)d_ws;
    ushort* fTr    = (ushort*)(ws);
    ushort* fTe    = (ushort*)(ws + 2097152);
    ushort* hTr    = (ushort*)(ws + 4194304);
    ushort* hTe    = (ushort*)(ws + 6291456);
    ushort* enhr   = (ushort*)(ws + 8388608);
    ushort* enhe   = (ushort*)(ws + 10485760);
    float*  featrT = (float*)(ws + 12582912);   // 4,194,304 f (fp32 NHWC, rgb)
    ushort* wA     = (ushort*)(ws + 16777216);  // 147456 bf16
    ushort* w2b    = (ushort*)(ws + 16850944);  // 409600 bf16
    ushort* wspb   = (ushort*)(ws + 17055744);  // 16384 bf16

    k_prep<<<2240, BLK, 0, stream>>>(w1, w2, wsp, wA, w2b, wspb);
    k_in_ln<<<2 * Bb * 256, BLK, 0, stream>>>(rgb, evt, w_in, lng, lnb,
                                              fTr, fTe, featrT);
    k_conv3<<<1024, BLK, 0, stream>>>(fTr, fTe, wA, hTr, hTe);
    k_dfapply<<<256, 512, 0, stream>>>(hTr, hTe, fTr, fTe, w2b, enhr, enhe);
    k_final<<<Bb * 256, BLK, 0, stream>>>(enhr, enhe, featrT, wspb, wout,
                                          lng, lnb, out);
}